// Round 13
// baseline (488.482 us; speedup 1.0000x reference)
//
#include <hip/hip_runtime.h>

// DILATE loss via the soft-DTW forward/backward identity:
//   E[i,j] = exp((V - R[i,j] - Rrev[i,j] + D[i,j]) / gamma)
// Round 13: BOTH direction passes in ONE 512-thread block (waves 0-3 dir0,
// waves 4-7 dir1). Each SIMD hosts 2 waves with identical schedules on
// independent data -> chain-latency bubbles (measured ~550cy/step at
// 1 wave/SIMD) are filled by the co-resident wave. Wave-level code is
// byte-identical to r12 (zero per-step LDS reads; DPP shr1; readlane
// boundary; packed valid-cell slab). Scaled domain R''=R*(100/ln2).

#define NSEQ 512
#define K2   144.269504088896f      // (1/gamma)*log2(e) = 100/ln2
#define SC   0.006931471805599453f  // ln2/100
#define BIGV 1e10f
#define ALPHA 0.5f
#define PACKN 262144                // N^2 floats per sample per direction

__device__ __forceinline__ int diag_off(int d) {
    if (d < 512) return (d * (d + 1)) >> 1;
    const int m = 1023 - d;
    return PACKN - ((m * (m + 1)) >> 1);
}

// full-wave shift toward higher lanes by 1 (lane l gets lane l-1); lane 0 -> BIGV
__device__ __forceinline__ float shr1(float v) {
    return __int_as_float(__builtin_amdgcn_update_dpp(
        __float_as_int(BIGV), __float_as_int(v), 0x138 /*wave_shr:1*/,
        0xF, 0xF, false));
}
__device__ __forceinline__ float rdlane(float v, int lane) {
    return __int_as_float(__builtin_amdgcn_readlane(__float_as_int(v), lane));
}

// o-ring element by static slot index: slot s holds o[j0s - 2 + s] (mod-8 slide)
#define OSLOT(s) ((s)==0?qp0.x:(s)==1?qp0.y:(s)==2?qp1.x:(s)==3?qp1.y: \
                  (s)==4?qp2.x:(s)==5?qp2.y:(s)==6?qp3.x:qp3.y)

__global__ __launch_bounds__(512) void sdtw_pass(
    const float* __restrict__ outp, const float* __restrict__ targ,
    float* __restrict__ slabA, float* __restrict__ slabB,
    float* __restrict__ vals, float* __restrict__ vraw, int kbase)
{
    const int tid  = threadIdx.x;
    const int dirg = tid >> 8;               // 0: forward pass, 1: reversed pass
    const int lt   = tid & 255;              // thread id within direction group
    const int w    = lt >> 6, l = tid & 63;
    const int i0   = 128 * w + 2 * l;        // lane owns rows i0, i0+1
    const int kk   = blockIdx.x;
    const int k    = kbase + kk;
    const bool lane0 = (l == 0), lane63 = (l == 63);

    __shared__ __align__(8) float o_pad[2][776];  // o[j] at [128+j], zeros outside
    __shared__ float t_sh[2][516];
    __shared__ float Rbf[2][3][644];  // boundary row 128(w+1)-1: col c at [c+1]

    for (int q = lt; q < 776; q += 256) o_pad[dirg][q] = 0.f;
    for (int q = lt; q < 516; q += 256) t_sh[dirg][q] = 0.f;
    __syncthreads();
    if (lt == 0) {
        Rbf[dirg][0][0] = BIGV; Rbf[dirg][1][0] = BIGV; Rbf[dirg][2][0] = BIGV;
    }
    for (int q = lt; q < NSEQ; q += 256) {   // dir 1: reversed sequences
        const int src = dirg ? (NSEQ - 1 - q) : q;
        o_pad[dirg][128 + q] = outp[(size_t)k * NSEQ + src];
        t_sh[dirg][q]        = targ[(size_t)k * NSEQ + src];
    }
    __syncthreads();

    const float t0 = t_sh[dirg][i0], t1 = t_sh[dirg][i0 + 1];
    const float* RbfR = Rbf[dirg][(w > 0 ? w : 1) - 1];   // only read when w > 0
    float*       RbfW = Rbf[dirg][w < 3 ? w : 2];         // only written when w < 3

    float* __restrict__ sp = (dirg ? slabB : slabA) + (size_t)kk * PACKN;

    float rp1_0 = BIGV, rp1_1 = BIGV, rp2_0 = BIGV, rp2_1 = BIGV;
    float sbv = BIGV;                        // carried shr1 value (prev sA)
    float rfinal = BIGV;
    float2 qp0, qp1, qp2, qp3;               // o register ring

    for (int ss = 0; ss < 19; ++ss) {
        const int mw = ss - 3 * w;               // wave-local window
        if (0 <= mw && mw < 10) {
            const int tb = (mw + 2 * w) * 64;    // global diag base
            const int j0s = tb - i0;             // lane's r=0 column at u=0
            if (mw == 0) {                       // prime ring: o[j0s-2 .. j0s+5]
                const float* ob = &o_pad[dirg][128 + j0s - 2];
                qp0 = *(const float2*)(ob);
                qp1 = *(const float2*)(ob + 2);
                qp2 = *(const float2*)(ob + 4);
                qp3 = *(const float2*)(ob + 6);
            }
            float bndv = BIGV, bdBc;             // boundary for lane0
            if (w) {
                bndv = RbfR[64 * mw + 1 + l];    // lane u: R[i0-1] col (64mw+u)
                bdBc = RbfR[64 * mw];            // broadcast: initial bdB
            } else {
                bdBc = (mw == 0) ? 0.f : BIGV;   // virtual R[-1,-1] = 0 at d=0
            }
            #pragma unroll 8
            for (int u = 0; u < 64; ++u) {       // diag d = tb + u
                if (u & 1) {                     // refill 2 slots, used 5 steps later
                    const float2 nv = *(const float2*)&o_pad[dirg][128 + j0s + u + 5];
                    const int p = ((u - 1) >> 1) & 3;
                    if (p == 0) qp0 = nv; else if (p == 1) qp1 = nv;
                    else if (p == 2) qp2 = nv; else qp3 = nv;
                }
                const float ojm = OSLOT((u + 1) & 7);  // o[j0s+u-1]
                const float oj  = OSLOT((u + 2) & 7);  // o[j0s+u]
                const float sA  = shr1(rp1_1);         // R[i0-1, j0] via DPP
                const float bdA = w ? rdlane(bndv, u) : BIGV;
                const float a0 = lane0 ? bdA : sA;     // R[i0-1, j0]
                const float b0 = lane0 ? bdBc : sbv;   // R[i0-1, j0-1]
                const float c0 = rp1_0;                // R[i0, j0-1]
                // cell r=0: (i0, j0): softmin = mn - log2(1 + 2^(mn-md) + 2^(mn-mx))
                float mn0 = fminf(fminf(a0, b0), c0);
                float mx0 = fmaxf(fmaxf(a0, b0), c0);
                float md0 = __builtin_amdgcn_fmed3f(a0, b0, c0);
                float s0 = 1.0f + __builtin_exp2f(mn0 - md0) + __builtin_exp2f(mn0 - mx0);
                float sm0 = mn0 - __builtin_log2f(s0);
                float dv0 = t0 - oj;
                float r0v = fmaf(dv0 * dv0, K2, sm0);
                // cell r=1: (i0+1, j0-1) — uses only pre-rotation registers
                float mn1 = fminf(fminf(rp1_0, rp2_0), rp1_1);
                float mx1 = fmaxf(fmaxf(rp1_0, rp2_0), rp1_1);
                float md1 = __builtin_amdgcn_fmed3f(rp1_0, rp2_0, rp1_1);
                float s1 = 1.0f + __builtin_exp2f(mn1 - md1) + __builtin_exp2f(mn1 - mx1);
                float sm1 = mn1 - __builtin_log2f(s1);
                float dv1 = t1 - ojm;
                float r1v = fmaf(dv1 * dv1, K2, sm1);
                const int jq = j0s + u;
                const bool act0 = ((unsigned)jq < 512u);
                const bool act1 = ((unsigned)(jq - 1) < 512u);
                const float r0n = act0 ? r0v : BIGV;
                const float r1n = act1 ? r1v : BIGV;
                rp2_0 = rp1_0; rp1_0 = r0n;
                rp2_1 = rp1_1; rp1_1 = r1n;
                sbv = sA;                             // next step's sB
                bdBc = bdA;                           // next step's bdB
                // packed store: only valid cells
                const int d = tb + u;
                const int ilo = (d > 511) ? (d - 511) : 0;
                const int basei = diag_off(d) - ilo;
                if (act0) sp[basei + i0]     = r0v;
                if (act1) sp[basei + i0 + 1] = r1v;
                if (lane63 && w < 3 && act1) RbfW[jq] = r1n;    // col jq-1 at [jq]
                if (u == 62 && mw == 9) rfinal = r1v;           // cell (511,511)
            }
        }
        asm volatile("s_waitcnt lgkmcnt(0)\n\ts_barrier" ::: "memory");
    }
    if (w == 3 && lane63 && dirg == 0) { vals[k] = rfinal * SC; vraw[k] = rfinal; }
}

// ---------------- pointwise E map-reduce ----------------
// E[i,j] = exp2(Vraw - A[i,j] - B[i',j'] + D[i,j]*K2); acc += E*(i-j)^2,
// with (i',j') = (511-i, 511-j) in the reverse pass's packed layout.
__global__ __launch_bounds__(256) void ereduce(
    const float* __restrict__ outp, const float* __restrict__ targ,
    const float* __restrict__ slabA, const float* __restrict__ slabB,
    const float* __restrict__ vraw, float* __restrict__ spart, int kbase)
{
    const int tid = threadIdx.x;
    const int sect = blockIdx.x & 15;
    const int kk = blockIdx.x >> 4;
    const int k = kbase + kk;

    __shared__ float t_sh[NSEQ], o_sh[NSEQ];
    __shared__ float red[4];
    for (int q = tid; q < NSEQ; q += 256) {
        t_sh[q] = targ[(size_t)k * NSEQ + q];
        o_sh[q] = outp[(size_t)k * NSEQ + q];
    }
    __syncthreads();

    const float* __restrict__ A  = slabA + (size_t)kk * PACKN;
    const float* __restrict__ Bs = slabB + (size_t)kk * PACKN;
    const float V = vraw[k];
    float acc = 0.f;
    const int dend = (sect == 15) ? 1023 : (sect * 64 + 64);
    for (int d = sect * 64; d < dend; ++d) {
        const int ilo = (d > 511) ? (d - 511) : 0;
        const int ihi = (d < 512) ? d : 511;
        const int dp  = 1022 - d;                       // reverse-pass diagonal
        const int iloB = (dp > 511) ? (dp - 511) : 0;
        const int baseA = diag_off(d) - ilo;
        const int baseB = diag_off(dp) + 511 - iloB;    // idxB = baseB - i
        for (int i = ilo + tid; i <= ihi; i += 256) {
            const float a = A[baseA + i];
            const float b = Bs[baseB - i];
            const float dv = t_sh[i] - o_sh[d - i];
            const float arg = fmaf(dv * dv, K2, V - a - b);
            const float E = __builtin_exp2f(arg);       // in [0, 1+eps]
            const float df = (float)(2 * i - d);        // i - j
            acc = fmaf(E * df, df, acc);
        }
    }
    for (int off = 32; off; off >>= 1) acc += __shfl_down(acc, off);
    if ((tid & 63) == 0) red[tid >> 6] = acc;
    __syncthreads();
    if (tid == 0) spart[k * 16 + sect] = red[0] + red[1] + red[2] + red[3];
}

__global__ void finalize_kernel(const float* __restrict__ vals,
                                const float* __restrict__ spart,
                                float* __restrict__ out, int B) {
    int t = threadIdx.x;    // 64 threads
    float v = 0.0f, s = 0.0f;
    for (int q = t; q < B; q += 64) v += vals[q];
    for (int q = t; q < 16 * B; q += 64) s += spart[q];
    for (int off = 32; off; off >>= 1) { v += __shfl_down(v, off); s += __shfl_down(s, off); }
    if (t == 0) {
        float loss_shape = v / (float)B;
        float loss_temporal = (s / (float)B) / ((float)NSEQ * (float)NSEQ);
        out[0] = ALPHA * loss_shape + (1.0f - ALPHA) * loss_temporal;
    }
}

extern "C" void kernel_launch(void* const* d_in, const int* in_sizes, int n_in,
                              void* d_out, int out_size, void* d_ws, size_t ws_size,
                              hipStream_t stream) {
    const float* outputs = (const float*)d_in[0];
    const float* targets = (const float*)d_in[1];
    const int B = in_sizes[0] / NSEQ;    // 64

    // ws: [0,256B) vals, [256,512B) vraw, [512,4608B) spart, [8192, ...) slabs
    float* vals  = (float*)d_ws;
    float* vraw  = vals + 64;
    float* spart = vals + 128;
    float* slabs = (float*)((char*)d_ws + 8192);

    const size_t per_sample = 2 * (size_t)PACKN * sizeof(float);   // 2 MiB (A+B)
    size_t avail = (ws_size > 8192) ? (ws_size - 8192) / per_sample : 0;
    int G = (int)((avail < (size_t)B) ? avail : (size_t)B);
    if (G < 1) G = 1;
    float* slabA = slabs;
    float* slabB = slabs + (size_t)G * PACKN;

    for (int kb = 0; kb < B; kb += G) {
        int g = (B - kb < G) ? (B - kb) : G;
        sdtw_pass<<<dim3(g), dim3(512), 0, stream>>>(
            outputs, targets, slabA, slabB, vals, vraw, kb);
        ereduce<<<dim3(16 * g), dim3(256), 0, stream>>>(
            outputs, targets, slabA, slabB, vraw, spart, kb);
    }
    finalize_kernel<<<dim3(1), dim3(64), 0, stream>>>(vals, spart, (float*)d_out, B);
}

// Round 14
// 328.432 us; speedup vs baseline: 1.4873x; 1.4873x over previous
//
#include <hip/hip_runtime.h>

// DILATE loss via the soft-DTW forward/backward identity:
//   E[i,j] = exp((V - R[i,j] - Rrev[i,j] + D[i,j]) / gamma)
// Round 14: r11 pass (313us, best) with BRANCH-FREE SKEWED STORES:
// one unconditional global_store_dwordx2 per lane per step at a pointer
// advancing 512B/step (no predication/exec-branches/diag_off math).
// Layout: cell (i,j) at float offset (i>>7)*65536 + (i+j)*128 + (i&127);
// 1.25 MiB per sample per direction (160 MiB total, one chunk).
// OOB garbage lands in never-read slots. ereduce reads stay coalesced
// within each 128-row band. Scaled domain R'' = R * (100/ln2).

#define NSEQ 512
#define K2   144.269504088896f      // (1/gamma)*log2(e) = 100/ln2
#define SC   0.006931471805599453f  // ln2/100
#define BIGV 1e10f
#define ALPHA 0.5f
#define PACKS 327680                // floats per sample per dir (4*640*128)

// full-wave shift toward higher lanes by 1 (lane l gets lane l-1); lane 0 -> BIGV
__device__ __forceinline__ float shr1(float v) {
    return __int_as_float(__builtin_amdgcn_update_dpp(
        __float_as_int(BIGV), __float_as_int(v), 0x138 /*wave_shr:1*/,
        0xF, 0xF, false));
}

__global__ __launch_bounds__(256) void sdtw_pass(
    const float* __restrict__ outp, const float* __restrict__ targ,
    float* __restrict__ slabA, float* __restrict__ slabB,
    float* __restrict__ vals, float* __restrict__ vraw, int kbase)
{
    const int tid = threadIdx.x;
    const int w = tid >> 6, l = tid & 63;
    const int i0 = 128 * w + 2 * l;          // lane owns rows i0, i0+1
    const int dir = blockIdx.x & 1;
    const int kk  = blockIdx.x >> 1;
    const int k   = kbase + kk;
    const bool lane0 = (l == 0), lane63 = (l == 63);

    __shared__ float o_pad[644];   // o[j] at [j+1], pads 0
    __shared__ float t_sh[516];
    __shared__ float Rbf[3][644];  // boundary row 128(w+1)-1 by column (col c at [c+1])
    __shared__ float dummyF[644];  // virtual row -1: [0]=0 (R[-1,-1]), else BIG

    for (int q = tid; q < 644; q += 256) { o_pad[q] = 0.f; dummyF[q] = BIGV; }
    for (int q = tid; q < 516; q += 256) t_sh[q] = 0.f;
    __syncthreads();
    if (tid == 0) {
        dummyF[0] = 0.f;                     // virtual R[-1,-1] = 0
        Rbf[0][0] = BIGV; Rbf[1][0] = BIGV; Rbf[2][0] = BIGV;
    }
    for (int q = tid; q < NSEQ; q += 256) {  // dir 1: reversed sequences
        const int src = dir ? (NSEQ - 1 - q) : q;
        o_pad[1 + q] = outp[(size_t)k * NSEQ + src];
        t_sh[q]      = targ[(size_t)k * NSEQ + src];
    }
    __syncthreads();

    const float t0 = t_sh[i0], t1 = t_sh[i0 + 1];
    const float* RbfR = (w == 0) ? dummyF : Rbf[w - 1];
    float*       RbfW = Rbf[w < 3 ? w : 2];          // guarded by (w<3)

    float2* __restrict__ slab2 =
        (float2*)((dir ? slabB : slabA) + (size_t)kk * PACKS);
    float2* __restrict__ sp2 = slab2 + w * 40960 + l;  // advances 64/step

    float rp1_0 = BIGV, rp1_1 = BIGV, rp2_0 = BIGV, rp2_1 = BIGV;
    float sbv = BIGV;                        // carried shr1(rp1_1) == previous sA
    float rfinal = BIGV;

    for (int ss = 0; ss < 19; ++ss) {
        const int mw = ss - 3 * w;               // wave-local window
        if (0 <= mw && mw < 10) {
            const int tb = (mw + 2 * w) * 64;    // global diag base
            int j0 = tb - i0;
            #pragma unroll 8
            for (int u = 0; u < 64; ++u, ++j0) {
                const int ob = (j0 > 0) ? j0 : 0;
                const float oj  = o_pad[ob + 1];     // o[j0]
                const float ojm = o_pad[ob];         // o[j0-1]
                const float bdA = RbfR[ob + 1];      // R[i0-1, j0]
                const float bdB = RbfR[ob];          // R[i0-1, j0-1]
                const float sA = shr1(rp1_1);        // R[i0-1, j0]   via DPP (diag d-1)
                const float sB = sbv;                // R[i0-1, j0-1] (carry of prev sA)
                const float a0 = lane0 ? bdA : sA;
                const float b0 = lane0 ? bdB : sB;
                const float c0 = rp1_0;
                // cell r=0: (i0, j0): softmin = mn - log2(1 + 2^(mn-md) + 2^(mn-mx))
                float mn0 = fminf(fminf(a0, b0), c0);
                float mx0 = fmaxf(fmaxf(a0, b0), c0);
                float md0 = __builtin_amdgcn_fmed3f(a0, b0, c0);
                float s0 = 1.0f + __builtin_exp2f(mn0 - md0) + __builtin_exp2f(mn0 - mx0);
                float sm0 = mn0 - __builtin_log2f(s0);
                float dv0 = t0 - oj;
                float r0v = fmaf(dv0 * dv0, K2, sm0);
                // cell r=1: (i0+1, j0-1) — uses only pre-rotation registers
                float mn1 = fminf(fminf(rp1_0, rp2_0), rp1_1);
                float mx1 = fmaxf(fmaxf(rp1_0, rp2_0), rp1_1);
                float md1 = __builtin_amdgcn_fmed3f(rp1_0, rp2_0, rp1_1);
                float s1 = 1.0f + __builtin_exp2f(mn1 - md1) + __builtin_exp2f(mn1 - mx1);
                float sm1 = mn1 - __builtin_log2f(s1);
                float dv1 = t1 - ojm;
                float r1v = fmaf(dv1 * dv1, K2, sm1);
                const bool act0 = ((unsigned)j0 < 512u);
                const bool act1 = ((unsigned)(j0 - 1) < 512u);
                const float r0n = act0 ? r0v : BIGV;
                const float r1n = act1 ? r1v : BIGV;
                rp2_0 = rp1_0; rp1_0 = r0n;
                rp2_1 = rp1_1; rp1_1 = r1n;
                sbv = sA;                             // becomes next step's sB
                // branch-free skewed store (garbage in never-read slots)
                sp2[0] = make_float2(r0v, r1v);
                sp2 += 64;
                if (lane63 && w < 3 && act1) RbfW[j0] = r1n;    // col j0-1 at [j0]
                if (u == 62 && mw == 9) rfinal = r1v;           // cell (511,511)
            }
        }
        asm volatile("s_waitcnt lgkmcnt(0)\n\ts_barrier" ::: "memory");
    }
    if (w == 3 && lane63 && dir == 0) { vals[k] = rfinal * SC; vraw[k] = rfinal; }
}

// ---------------- pointwise E map-reduce ----------------
// E[i,j] = exp2(Vraw - A[i,j] - B[i',j'] + D[i,j]*K2); acc += E*(i-j)^2,
// with (i',j') = (511-i, 511-j) in the reverse pass's skewed layout.
// float offset of cell (i,j): (i>>7)*65536 + (i+j)*128 + (i&127).
__global__ __launch_bounds__(256) void ereduce(
    const float* __restrict__ outp, const float* __restrict__ targ,
    const float* __restrict__ slabA, const float* __restrict__ slabB,
    const float* __restrict__ vraw, float* __restrict__ spart, int kbase)
{
    const int tid = threadIdx.x;
    const int sect = blockIdx.x & 15;
    const int kk = blockIdx.x >> 4;
    const int k = kbase + kk;

    __shared__ float t_sh[NSEQ], o_sh[NSEQ];
    __shared__ float red[4];
    for (int q = tid; q < NSEQ; q += 256) {
        t_sh[q] = targ[(size_t)k * NSEQ + q];
        o_sh[q] = outp[(size_t)k * NSEQ + q];
    }
    __syncthreads();

    const float* __restrict__ A  = slabA + (size_t)kk * PACKS;
    const float* __restrict__ Bs = slabB + (size_t)kk * PACKS;
    const float V = vraw[k];
    float acc = 0.f;
    const int dend = (sect == 15) ? 1023 : (sect * 64 + 64);
    for (int d = sect * 64; d < dend; ++d) {
        const int ilo = (d > 511) ? (d - 511) : 0;
        const int ihi = (d < 512) ? d : 511;
        const int dbA = d * 128;
        const int dbB = (1022 - d) * 128;
        for (int i = ilo + tid; i <= ihi; i += 256) {
            const int i2 = 511 - i;
            const float a = A [((i  >> 7) << 16) + dbA + (i  & 127)];
            const float b = Bs[((i2 >> 7) << 16) + dbB + (i2 & 127)];
            const float dv = t_sh[i] - o_sh[d - i];
            const float arg = fmaf(dv * dv, K2, V - a - b);
            const float E = __builtin_exp2f(arg);       // in [0, 1+eps]
            const float df = (float)(2 * i - d);        // i - j
            acc = fmaf(E * df, df, acc);
        }
    }
    for (int off = 32; off; off >>= 1) acc += __shfl_down(acc, off);
    if ((tid & 63) == 0) red[tid >> 6] = acc;
    __syncthreads();
    if (tid == 0) spart[k * 16 + sect] = red[0] + red[1] + red[2] + red[3];
}

__global__ void finalize_kernel(const float* __restrict__ vals,
                                const float* __restrict__ spart,
                                float* __restrict__ out, int B) {
    int t = threadIdx.x;    // 64 threads
    float v = 0.0f, s = 0.0f;
    for (int q = t; q < B; q += 64) v += vals[q];
    for (int q = t; q < 16 * B; q += 64) s += spart[q];
    for (int off = 32; off; off >>= 1) { v += __shfl_down(v, off); s += __shfl_down(s, off); }
    if (t == 0) {
        float loss_shape = v / (float)B;
        float loss_temporal = (s / (float)B) / ((float)NSEQ * (float)NSEQ);
        out[0] = ALPHA * loss_shape + (1.0f - ALPHA) * loss_temporal;
    }
}

extern "C" void kernel_launch(void* const* d_in, const int* in_sizes, int n_in,
                              void* d_out, int out_size, void* d_ws, size_t ws_size,
                              hipStream_t stream) {
    const float* outputs = (const float*)d_in[0];
    const float* targets = (const float*)d_in[1];
    const int B = in_sizes[0] / NSEQ;    // 64

    // ws: [0,256B) vals, [256,512B) vraw, [512,4608B) spart, [8192, ...) slabs
    float* vals  = (float*)d_ws;
    float* vraw  = vals + 64;
    float* spart = vals + 128;
    float* slabs = (float*)((char*)d_ws + 8192);

    const size_t per_sample = 2 * (size_t)PACKS * sizeof(float);   // 2.5 MiB (A+B)
    size_t avail = (ws_size > 8192) ? (ws_size - 8192) / per_sample : 0;
    int G = (int)((avail < (size_t)B) ? avail : (size_t)B);
    if (G < 1) G = 1;
    float* slabA = slabs;
    float* slabB = slabs + (size_t)G * PACKS;

    for (int kb = 0; kb < B; kb += G) {
        int g = (B - kb < G) ? (B - kb) : G;
        sdtw_pass<<<dim3(2 * g), dim3(256), 0, stream>>>(
            outputs, targets, slabA, slabB, vals, vraw, kb);
        ereduce<<<dim3(16 * g), dim3(256), 0, stream>>>(
            outputs, targets, slabA, slabB, vraw, spart, kb);
    }
    finalize_kernel<<<dim3(1), dim3(64), 0, stream>>>(vals, spart, (float*)d_out, B);
}